// Round 8
// baseline (427.220 us; speedup 1.0000x reference)
//
#include <hip/hip_runtime.h>
#include <math.h>

#define BB 8
#define TT 512
#define DD 256
#define DIM 512
#define KW 4
#define MM 2
#define HH 4
#define HDIM 64
#define LL 2
#define VV 272

typedef __attribute__((ext_vector_type(8))) short bf16x8;
typedef __attribute__((ext_vector_type(4))) float f32x4;

__device__ __forceinline__ float sigf(float x){ return 1.f/(1.f+__expf(-x)); }
__device__ __forceinline__ float siluf(float x){ return x/(1.f+__expf(-x)); }

__device__ __forceinline__ unsigned short f2bf(float f){
  unsigned int u = __float_as_uint(f);
  unsigned int r = (u + 0x7FFFu + ((u >> 16) & 1u)) >> 16;
  return (unsigned short)r;
}

// d-reduce via DPP only (no DS ops): xor1/xor2 = quad_perm, xor8 = row_ror:8
__device__ __forceinline__ float xor1_add(float x){
  int y = __builtin_amdgcn_update_dpp(0, __float_as_int(x), 0xB1, 0xF, 0xF, true);
  return x + __int_as_float(y);
}
__device__ __forceinline__ float xor2_add(float x){
  int y = __builtin_amdgcn_update_dpp(0, __float_as_int(x), 0x4E, 0xF, 0xF, true);
  return x + __int_as_float(y);
}
__device__ __forceinline__ float xor8_add(float x){
  int y = __builtin_amdgcn_update_dpp(0, __float_as_int(x), 0x128, 0xF, 0xF, true);
  return x + __int_as_float(y);
}

// async global->LDS, 16B per lane. LDS dest is wave-uniform base + lane*16.
__device__ __forceinline__ void gl_lds16(const float* g, float* l){
  __builtin_amdgcn_global_load_lds(
      (const __attribute__((address_space(1))) unsigned int*)g,
      (__attribute__((address_space(3))) unsigned int*)l,
      16, 0, 0);
}

// ---------------- embedding gather ----------------
__global__ void k_embed(const int* __restrict__ ids, const float* __restrict__ emb,
                        float* __restrict__ x){
  int row = blockIdx.x;
  int d = threadIdx.x;
  x[row*DD + d] = emb[ids[row]*DD + d];
}

// ---------------- rmsnorm (row of 256), 1 wave/row ----------------
__global__ void k_rmsnorm(const float* __restrict__ in, const float* __restrict__ w,
                          float* __restrict__ out){
  int row = blockIdx.x;
  int l = threadIdx.x;             // 64
  float4 v = *(const float4*)&in[row*DD + l*4];
  float ss = v.x*v.x + v.y*v.y + v.z*v.z + v.w*v.w;
  #pragma unroll
  for (int o = 32; o > 0; o >>= 1) ss += __shfl_xor(ss, o, 64);
  float sc = rsqrtf(ss*(1.f/DD) + 1e-6f);
  float4 wv = *(const float4*)&w[l*4];
  float4 r;
  r.x = v.x*sc*wv.x; r.y = v.y*sc*wv.y; r.z = v.z*sc*wv.z; r.w = v.w*sc*wv.w;
  *(float4*)&out[row*DD + l*4] = r;
}

// ---------------- bf16 MFMA GEMM: C[4096,N] = A[4096,K] @ B ----------------
template<bool BT>
__global__ void __launch_bounds__(256) k_gemm_bf(const float* __restrict__ A,
                                                 const float* __restrict__ B,
                                                 float* __restrict__ C, int N, int K){
  __shared__ unsigned short as[64][88];
  __shared__ unsigned short bs[64][88];
  const int tid = threadIdx.x;
  const int w = tid >> 6, l = tid & 63;
  const int m0 = blockIdx.y*64, n0 = blockIdx.x*64;
  f32x4 acc[4] = {};
  for (int k0 = 0; k0 < K; k0 += 64){
    { int ar = tid >> 2, ac = (tid & 3)*16;
      #pragma unroll
      for (int j = 0; j < 4; ++j){
        float4 a = *(const float4*)&A[(size_t)(m0+ar)*K + k0 + ac + j*4];
        ushort4 u = make_ushort4(f2bf(a.x), f2bf(a.y), f2bf(a.z), f2bf(a.w));
        *(ushort4*)&as[ar][ac + j*4] = u;
      }
    }
    if (!BT){
      int kr = tid >> 2, nc = (tid & 3)*16;
      #pragma unroll
      for (int j = 0; j < 4; ++j){
        int n = n0 + nc + j*4;
        float4 bv = make_float4(0.f,0.f,0.f,0.f);
        if (n < N) bv = *(const float4*)&B[(size_t)(k0+kr)*N + n];
        bs[nc+j*4+0][kr] = f2bf(bv.x);
        bs[nc+j*4+1][kr] = f2bf(bv.y);
        bs[nc+j*4+2][kr] = f2bf(bv.z);
        bs[nc+j*4+3][kr] = f2bf(bv.w);
      }
    } else {
      int nr = tid >> 2, kc = (tid & 3)*16;
      int n = n0 + nr;
      #pragma unroll
      for (int j = 0; j < 4; ++j){
        float4 bv = make_float4(0.f,0.f,0.f,0.f);
        if (n < N) bv = *(const float4*)&B[(size_t)n*K + k0 + kc + j*4];
        ushort4 u = make_ushort4(f2bf(bv.x), f2bf(bv.y), f2bf(bv.z), f2bf(bv.w));
        *(ushort4*)&bs[nr][kc + j*4] = u;
      }
    }
    __syncthreads();
    const int mr = w*16 + (l & 15);
    const int kb = (l >> 4)*8;
    #pragma unroll
    for (int kc2 = 0; kc2 < 2; ++kc2){
      bf16x8 af = *(const bf16x8*)&as[mr][kc2*32 + kb];
      #pragma unroll
      for (int nt = 0; nt < 4; ++nt){
        bf16x8 bfr = *(const bf16x8*)&bs[nt*16 + (l & 15)][kc2*32 + kb];
        acc[nt] = __builtin_amdgcn_mfma_f32_16x16x32_bf16(af, bfr, acc[nt], 0, 0, 0);
      }
    }
    __syncthreads();
  }
  #pragma unroll
  for (int nt = 0; nt < 4; ++nt){
    int col = n0 + nt*16 + (l & 15);
    if (col < N){
      #pragma unroll
      for (int r = 0; r < 4; ++r){
        int row = m0 + w*16 + (l >> 4)*4 + r;
        C[(size_t)row*N + col] = acc[nt][r];
      }
    }
  }
}

// ---- Wout GEMM with fused comb (A = p0+p1) and resid (x += y + A@Wout) ----
__global__ void __launch_bounds__(256) k_gemm_wout(const float* __restrict__ p0,
                                                   const float* __restrict__ p1,
                                                   const float* __restrict__ B,
                                                   const float* __restrict__ y,
                                                   float* __restrict__ x){
  __shared__ unsigned short as[64][88];
  __shared__ unsigned short bs[64][88];
  const int tid = threadIdx.x;
  const int w = tid >> 6, l = tid & 63;
  const int m0 = blockIdx.y*64, n0 = blockIdx.x*64;
  f32x4 acc[4] = {};
  for (int k0 = 0; k0 < DD; k0 += 64){
    { int ar = tid >> 2, ac = (tid & 3)*16;
      #pragma unroll
      for (int j = 0; j < 4; ++j){
        size_t off = (size_t)(m0+ar)*DD + k0 + ac + j*4;
        float4 a = *(const float4*)&p0[off];
        float4 b = *(const float4*)&p1[off];
        a.x += b.x; a.y += b.y; a.z += b.z; a.w += b.w;
        ushort4 u = make_ushort4(f2bf(a.x), f2bf(a.y), f2bf(a.z), f2bf(a.w));
        *(ushort4*)&as[ar][ac + j*4] = u;
      }
    }
    { int kr = tid >> 2, nc = (tid & 3)*16;
      #pragma unroll
      for (int j = 0; j < 4; ++j){
        float4 bv = *(const float4*)&B[(size_t)(k0+kr)*DD + n0 + nc + j*4];
        bs[nc+j*4+0][kr] = f2bf(bv.x);
        bs[nc+j*4+1][kr] = f2bf(bv.y);
        bs[nc+j*4+2][kr] = f2bf(bv.z);
        bs[nc+j*4+3][kr] = f2bf(bv.w);
      }
    }
    __syncthreads();
    const int mr = w*16 + (l & 15);
    const int kb = (l >> 4)*8;
    #pragma unroll
    for (int kc2 = 0; kc2 < 2; ++kc2){
      bf16x8 af = *(const bf16x8*)&as[mr][kc2*32 + kb];
      #pragma unroll
      for (int nt = 0; nt < 4; ++nt){
        bf16x8 bfr = *(const bf16x8*)&bs[nt*16 + (l & 15)][kc2*32 + kb];
        acc[nt] = __builtin_amdgcn_mfma_f32_16x16x32_bf16(af, bfr, acc[nt], 0, 0, 0);
      }
    }
    __syncthreads();
  }
  #pragma unroll
  for (int nt = 0; nt < 4; ++nt){
    int col = n0 + nt*16 + (l & 15);
    #pragma unroll
    for (int r = 0; r < 4; ++r){
      int row = m0 + w*16 + (l >> 4)*4 + r;
      size_t off = (size_t)row*DD + col;
      x[off] = x[off] + y[off] + acc[nt][r];
    }
  }
}

// ---------------- f32 GEMM (small-N path, proj only) ----------------
template<bool BT>
__global__ void __launch_bounds__(128) k_gemm(const float* __restrict__ A,
                                              const float* __restrict__ B,
                                              float* __restrict__ C, int N, int K){
  __shared__ float as[16][68];
  __shared__ float bs[16][68];
  const int tid = threadIdx.x;
  const int tx = tid & 15, ty = tid >> 4;
  const int m0 = blockIdx.y * 64, n0 = blockIdx.x * 64;
  float acc[8][4] = {};
  for (int k0 = 0; k0 < K; k0 += 16){
    #pragma unroll
    for (int r = 0; r < 2; ++r){
      int idx = tid + r*128;
      int mm = idx >> 2, kk4 = (idx & 3) * 4;
      float4 a = *(const float4*)&A[(size_t)(m0+mm)*K + k0 + kk4];
      as[kk4+0][mm] = a.x; as[kk4+1][mm] = a.y; as[kk4+2][mm] = a.z; as[kk4+3][mm] = a.w;
    }
    if (!BT){
      #pragma unroll
      for (int r = 0; r < 2; ++r){
        int idx = tid + r*128;
        int kk = idx >> 4, nn4 = (idx & 15) * 4;
        int n = n0 + nn4;
        float4 b = make_float4(0.f,0.f,0.f,0.f);
        if (n < N) b = *(const float4*)&B[(size_t)(k0+kk)*N + n];
        *(float4*)&bs[kk][nn4] = b;
      }
    } else {
      int nn = tid >> 1, kk8 = (tid & 1) * 8;
      int n = n0 + nn;
      float4 b0 = make_float4(0.f,0.f,0.f,0.f), b1 = b0;
      if (n < N){
        b0 = *(const float4*)&B[(size_t)n*K + k0 + kk8];
        b1 = *(const float4*)&B[(size_t)n*K + k0 + kk8 + 4];
      }
      bs[kk8+0][nn]=b0.x; bs[kk8+1][nn]=b0.y; bs[kk8+2][nn]=b0.z; bs[kk8+3][nn]=b0.w;
      bs[kk8+4][nn]=b1.x; bs[kk8+5][nn]=b1.y; bs[kk8+6][nn]=b1.z; bs[kk8+7][nn]=b1.w;
    }
    __syncthreads();
    #pragma unroll
    for (int kk = 0; kk < 16; ++kk){
      float ar[8], br[4];
      *(float4*)&ar[0] = *(const float4*)&as[kk][ty*4];
      *(float4*)&ar[4] = *(const float4*)&as[kk][32+ty*4];
      *(float4*)&br[0] = *(const float4*)&bs[kk][tx*4];
      #pragma unroll
      for (int i = 0; i < 8; ++i)
        #pragma unroll
        for (int j = 0; j < 4; ++j) acc[i][j] = fmaf(ar[i], br[j], acc[i][j]);
    }
    __syncthreads();
  }
  int n = n0 + tx*4;
  if (n < N){
    #pragma unroll
    for (int i = 0; i < 8; ++i){
      int row = m0 + ((i < 4) ? (ty*4 + i) : (32 + ty*4 + i - 4));
      float4 r; r.x=acc[i][0]; r.y=acc[i][1]; r.z=acc[i][2]; r.w=acc[i][3];
      *(float4*)&C[(size_t)row*N + n] = r;
    }
  }
}

// ---------------- causal depthwise conv + silu gating --------
__global__ void k_conv(const float* __restrict__ u, const float* __restrict__ g,
                       const float* __restrict__ cw, const float* __restrict__ cb,
                       float* __restrict__ hh){
  int idx = blockIdx.x*256 + threadIdx.x;
  int c  = idx % DIM;
  int bt = idx / DIM;
  int t  = bt % TT;
  float acc = cb[c];
  #pragma unroll
  for (int j = 0; j < KW; ++j){
    int dt_ = j - (KW-1);
    if (t + dt_ >= 0) acc = fmaf(u[(bt + dt_)*DIM + c], cw[c*KW + j], acc);
  }
  float h = siluf(acc);
  hh[idx] = siluf(g[idx]) * h;
}

// ---------------- pack small projection weights into (D, 28) ----------------
__global__ void k_pack(const float* __restrict__ Wg, const float* __restrict__ Wb,
                       const float* __restrict__ Wa, const float* __restrict__ Wbl,
                       float* __restrict__ Wp){
  int d = blockIdx.x;
  int j = threadIdx.x;
  if (j >= 28) return;
  float v;
  if (j < 4)        v = Wg[d*HH + j];
  else if (j < 12){ int m=(j-4)>>2, h=(j-4)&3;  v = Wb[(m*DD + d)*HH + h]; }
  else if (j < 20){ int m=(j-12)>>2, h=(j-12)&3; v = Wa[(m*DD + d)*HH + h]; }
  else              v = Wbl[d*(HH*MM) + (j-20)];
  Wp[d*28 + j] = v;
}

// ---------------- rk normalization ----------
__global__ void k_rk(const float* __restrict__ y, float* __restrict__ rkb){
  int blk = blockIdx.x;
  int lane = threadIdx.x;
  int row = blk >> 2, h = blk & 3;
  float v = y[row*DD + h*HDIM + lane];
  float ss = v*v;
  #pragma unroll
  for (int o = 32; o > 0; o >>= 1) ss += __shfl_xor(ss, o, 64);
  float nrm = fmaxf(sqrtf(ss), 1e-12f);
  rkb[row*DD + h*HDIM + lane] = v / nrm;
}

// ---------------- precompute scan scalars ----------
__global__ void k_scal(const float* __restrict__ proj, const float* __restrict__ A_log,
                       const float* __restrict__ dtb, float* __restrict__ scal){
  int i = blockIdx.x*256 + threadIdx.x;
  int mh = i & 7;
  int row = i >> 3;
  int m = mh >> 2, h = mh & 3;
  const float* pv = proj + (size_t)row*28;
  float gs  = sigf(pv[h]);
  float btv = sigf(pv[4 + m*4 + h]);
  float sp  = pv[12 + m*4 + h] + dtb[m*HH + h];
  sp = (sp > 15.f) ? sp : log1pf(__expf(sp));
  float dc  = __expf(-__expf(A_log[m*HH + h]) * sp);
  float l0 = pv[20 + h*2], l1 = pv[20 + h*2 + 1];
  float mx = fmaxf(l0, l1);
  float e0 = __expf(l0-mx), e1 = __expf(l1-mx);
  float bl = (m ? e1 : e0) / (e0 + e1);
  float4 o; o.x = dc; o.y = btv; o.z = bl*gs; o.w = 0.f;
  *(float4*)&scal[((size_t)row*MM + m)*(HH*4) + h*4] = o;
}

// ---------------- sequential delta-memory scan ----------
// grid = B*H*M*8 blocks (k-split by 8), 64 threads = 1 wave.
// Lane bits {0,1,3} = d-octant q (8 d each, S[8]/lane); bits {2,4,5} = k.
// DEPTH-4 register prefetch: period-8 slot rotation (r0..r7 rk, v0..v7, c0..c7),
// inner loop unrolled x8, prefetch at step START. Prologue reloads slots 0..3
// per chunk (cross-chunk wk continuity carried in slot 7, never touched there).

#define SSTEP(T_, RPRV, RCUR, RPF, VC, VPF, SC, SPF) { \
  const float dc = SC.x, btv = SC.y, blg = SC.z; \
  const float v = VC; \
  { const int tn_ = ((T_)+4 < 64) ? (T_)+4 : 63; \
    RPF[0] = *(const float4*)&s_rk[p][tn_][dbase + 0]; \
    RPF[1] = *(const float4*)&s_rk[p][tn_][dbase + 4]; \
    VPF = s_v[p][tn_][klocal]; \
    SPF = *(const float4*)&s_sc[p][tn_][0]; } \
  float pp0=0.f,pp1=0.f; \
  { const float4 r0_ = RPRV[0], r1_ = RPRV[1]; \
    if (ROT == 0){ \
      pp0 = fmaf(S[0], r0_.x, pp0); pp0 = fmaf(S[1], r0_.y, pp0); \
      pp0 = fmaf(S[2], r0_.z, pp0); pp0 = fmaf(S[3], r0_.w, pp0); \
      pp1 = fmaf(S[4], r1_.x, pp1); pp1 = fmaf(S[5], r1_.y, pp1); \
      pp1 = fmaf(S[6], r1_.z, pp1); pp1 = fmaf(S[7], r1_.w, pp1); \
    } else { \
      pp0 = fmaf(S[0], -r0_.y, pp0); pp0 = fmaf(S[1], r0_.x, pp0); \
      pp0 = fmaf(S[2], -r0_.w, pp0); pp0 = fmaf(S[3], r0_.z, pp0); \
      pp1 = fmaf(S[4], -r1_.y, pp1); pp1 = fmaf(S[5], r1_.x, pp1); \
      pp1 = fmaf(S[6], -r1_.w, pp1); pp1 = fmaf(S[7], r1_.z, pp1); } } \
  float pp = pp0 + pp1; \
  pp = xor1_add(pp); pp = xor2_add(pp); pp = xor8_add(pp); \
  const float err = (v - dc*pp)*btv; \
  float rr0=0.f,rr1=0.f; \
  _Pragma("unroll") \
  for (int j = 0; j < 2; ++j){ const float4 rp = RPRV[j]; const float4 rc = RCUR[j]; \
    float w0,w1,w2,w3,c0_,c1_,c2_,c3_; \
    if (ROT == 0){ w0=rp.x; w1=rp.y; w2=rp.z; w3=rp.w; c0_=rc.x; c1_=rc.y; c2_=rc.z; c3_=rc.w; } \
    else { w0=-rp.y; w1=rp.x; w2=-rp.w; w3=rp.z; c0_=-rc.y; c1_=rc.x; c2_=-rc.w; c3_=rc.z; } \
    S[4*j+0] = fmaf(S[4*j+0], dc, w0*err); rr0 = fmaf(S[4*j+0], c0_, rr0); \
    S[4*j+1] = fmaf(S[4*j+1], dc, w1*err); rr1 = fmaf(S[4*j+1], c1_, rr1); \
    S[4*j+2] = fmaf(S[4*j+2], dc, w2*err); rr0 = fmaf(S[4*j+2], c2_, rr0); \
    S[4*j+3] = fmaf(S[4*j+3], dc, w3*err); rr1 = fmaf(S[4*j+3], c3_, rr1); } \
  float rr = rr0 + rr1; \
  rr = xor1_add(rr); rr = xor2_add(rr); rr = xor8_add(rr); \
  if (q == 0) part[(size_t)(rowchunk + (T_))*DD + h*HDIM + kq*8 + klocal] = blg*rr; \
}

template<int ROT>
__device__ __forceinline__ void scan_body(int b, int h, int kq, int l,
    const float* __restrict__ vals, const float* __restrict__ rkb,
    const float* __restrict__ scal, float* __restrict__ part,
    float (*s_rk)[64][64], float (*s_v)[64][8], float (*s_sc)[64][4])
{
  const int q = (l & 3) | ((l & 8) >> 1);             // bits 0,1,3
  const int klocal = ((l >> 2) & 1) | ((l >> 3) & 6); // bits 2,4,5
  const int dbase = q*8;
  const int rowbase = b*TT;

  float S[8];
  #pragma unroll
  for (int j = 0; j < 8; ++j) S[j] = 0.f;
  const float4 Z = make_float4(0.f,0.f,0.f,0.f);
  float4 r0[2]={Z,Z}, r1[2]={Z,Z}, r2[2]={Z,Z}, r3[2]={Z,Z};
  float4 r4[2]={Z,Z}, r5[2]={Z,Z}, r6[2]={Z,Z}, r7[2]={Z,Z};
  float v0=0.f,v1=0.f,v2=0.f,v3=0.f,v4=0.f,v5=0.f,v6=0.f,v7=0.f;
  float4 c0=Z,c1=Z,c2=Z,c3=Z,c4=Z,c5=Z,c6=Z,c7=Z;

  auto stage = [&](int c, int pbuf){
    const int r0g = rowbase + c*64;
    #pragma unroll
    for (int i = 0; i < 16; ++i){
      const float* g = rkb + (size_t)(r0g + i*4 + (l>>4))*DD + h*HDIM + (l&15)*4;
      gl_lds16(g, &s_rk[pbuf][i*4][0]);
    }
    #pragma unroll
    for (int i = 0; i < 2; ++i){
      const float* g = vals + ((size_t)(r0g + i*32 + (l>>1))*MM + ROT)*DD + h*HDIM + kq*8 + (l&1)*4;
      gl_lds16(g, &s_v[pbuf][i*32][0]);
    }
    { const float* g = scal + ((size_t)(r0g + l)*MM + ROT)*(HH*4) + h*4;
      gl_lds16(g, &s_sc[pbuf][0][0]); }
  };

  stage(0, 0);
  for (int c = 0; c < TT/64; ++c){
    const int p = c & 1;
    __syncthreads();                 // vmcnt drain: chunk c staged
    if (c + 1 < TT/64) stage(c+1, p^1);
    // prologue: slots 0..3 for this chunk (slot 7 = cross-chunk wk, untouched)
    r0[0] = *(const float4*)&s_rk[p][0][dbase]; r0[1] = *(const float4*)&s_rk[p][0][dbase+4];
    r1[0] = *(const float4*)&s_rk[p][1][dbase]; r1[1] = *(const float4*)&s_rk[p][1][dbase+4];
    r2[0] = *(const float4*)&s_rk[p][2][dbase]; r2[1] = *(const float4*)&s_rk[p][2][dbase+4];
    r3[0] = *(const float4*)&s_rk[p][3][dbase]; r3[1] = *(const float4*)&s_rk[p][3][dbase+4];
    v0 = s_v[p][0][klocal]; v1 = s_v[p][1][klocal];
    v2 = s_v[p][2][klocal]; v3 = s_v[p][3][klocal];
    c0 = *(const float4*)&s_sc[p][0][0]; c1 = *(const float4*)&s_sc[p][1][0];
    c2 = *(const float4*)&s_sc[p][2][0]; c3 = *(const float4*)&s_sc[p][3][0];
    const int rowchunk = rowbase + c*64;
    for (int tt = 0; tt < 64; tt += 8){
      SSTEP(tt+0, r7, r0, r4, v0, v4, c0, c4)
      SSTEP(tt+1, r0, r1, r5, v1, v5, c1, c5)
      SSTEP(tt+2, r1, r2, r6, v2, v6, c2, c6)
      SSTEP(tt+3, r2, r3, r7, v3, v7, c3, c7)
      SSTEP(tt+4, r3, r4, r0, v4, v0, c4, c0)
      SSTEP(tt+5, r4, r5, r1, v5, v1, c5, c1)
      SSTEP(tt+6, r5, r6, r2, v6, v2, c6, c2)
      SSTEP(tt+7, r6, r7, r3, v7, v3, c7, c3)
    }
  }
}

__global__ void __launch_bounds__(64) k_scan(const float* __restrict__ vals,
                                             const float* __restrict__ rkb,
                                             const float* __restrict__ scal,
                                             float* __restrict__ partials){
  __shared__ float s_rk[2][64][64];
  __shared__ float s_v [2][64][8];
  __shared__ float s_sc[2][64][4];
  const int bi = blockIdx.x;      // (((b*HH)+h)*MM + m)*8 + kq
  const int kq = bi & 7;
  const int m  = (bi >> 3) & 1;
  const int h  = (bi >> 4) & 3;
  const int b  = bi >> 6;
  float* part = partials + (size_t)m*(BB*TT*DD);
  if (m == 0) scan_body<0>(b, h, kq, threadIdx.x, vals, rkb, scal, part, s_rk, s_v, s_sc);
  else        scan_body<1>(b, h, kq, threadIdx.x, vals, rkb, scal, part, s_rk, s_v, s_sc);
}

extern "C" void kernel_launch(void* const* d_in, const int* in_sizes, int n_in,
                              void* d_out, int out_size, void* d_ws, size_t ws_size,
                              hipStream_t stream){
  const int*   ids   = (const int*)d_in[0];
  const float* emb   = (const float*)d_in[1];
  const float* normw = (const float*)d_in[2];
  const float* Wup   = (const float*)d_in[3];
  const float* Wgate = (const float*)d_in[4];
  const float* Wdown = (const float*)d_in[5];
  const float* convw = (const float*)d_in[6];
  const float* convb = (const float*)d_in[7];
  const float* Wv    = (const float*)d_in[8];
  const float* Wg    = (const float*)d_in[9];
  const float* Wb    = (const float*)d_in[10];
  const float* Wa    = (const float*)d_in[11];
  const float* A_log = (const float*)d_in[12];
  const float* dtb   = (const float*)d_in[13];
  const float* Wbl   = (const float*)d_in[14];
  const float* Wout  = (const float*)d_in[15];
  const float* fnw   = (const float*)d_in[16];
  float* out = (float*)d_out;

  const int ROWS = BB*TT;              // 4096
  const size_t MEG = 1u << 20;
  float* ws   = (float*)d_ws;
  float* x    = ws;                    // 1M
  float* nx   = x    + MEG;            // 1M
  float* big1 = nx   + MEG;            // 2M : u, then vals
  float* big2 = big1 + 2*MEG;          // 2M : g/hh, then partials
  float* y    = big2 + 2*MEG;          // 1M
  float* proj = y    + MEG;            // 128K
  float* rkb  = proj + (1u<<17);       // 1M
  float* Wp   = rkb  + MEG;            // 8K
  float* scal = Wp   + 8192;           // 128K

  k_embed<<<ROWS, DD, 0, stream>>>(ids, emb, x);

  for (int l = 0; l < LL; ++l){
    k_rmsnorm<<<ROWS, 64, 0, stream>>>(x, normw + l*DD, nx);
    float* u = big1; float* g = big2;
    k_gemm_bf<false><<<dim3(DIM/64, ROWS/64), 256, 0, stream>>>(nx, Wup + (size_t)l*DD*DIM, u, DIM, DD);
    k_gemm_bf<false><<<dim3(DIM/64, ROWS/64), 256, 0, stream>>>(nx, Wgate + (size_t)l*DD*DIM, g, DIM, DD);
    k_conv<<<(ROWS*DIM)/256, 256, 0, stream>>>(u, g, convw + l*DIM*KW, convb + l*DIM, g);
    k_gemm_bf<false><<<dim3(DD/64, ROWS/64), 256, 0, stream>>>(g, Wdown + (size_t)l*DIM*DD, y, DD, DIM);
    float* vals = big1;
    k_gemm_bf<false><<<dim3((MM*DD)/64, ROWS/64), 256, 0, stream>>>(y, Wv + (size_t)l*DD*MM*DD, vals, MM*DD, DD);
    k_pack<<<DD, 32, 0, stream>>>(Wg + l*DD*HH, Wb + l*MM*DD*HH, Wa + l*MM*DD*HH,
                                  Wbl + l*DD*HH*MM, Wp);
    k_gemm<false><<<dim3(1, ROWS/64), 128, 0, stream>>>(y, Wp, proj, 28, DD);
    k_scal<<<(ROWS*MM*HH)/256, 256, 0, stream>>>(proj, A_log + l*MM*HH, dtb + l*MM*HH, scal);
    k_rk<<<ROWS*HH, 64, 0, stream>>>(y, rkb);
    k_scan<<<BB*HH*MM*8, 64, 0, stream>>>(vals, rkb, scal, big2);
    // fused: x += y + (p0+p1)@Wout
    k_gemm_wout<<<dim3(DD/64, ROWS/64), 256, 0, stream>>>(big2, big2 + MEG,
                                                          Wout + (size_t)l*DD*DD, y, x);
  }

  k_rmsnorm<<<ROWS, 64, 0, stream>>>(x, fnw, nx);
  k_gemm_bf<true><<<dim3((VV+63)/64, ROWS/64), 256, 0, stream>>>(nx, emb, out, VV, DD);
}